// Round 2
// baseline (3482.174 us; speedup 1.0000x reference)
//
#include <hip/hip_runtime.h>
#include <hip/hip_bf16.h>
#include <cstdio>

// Problem constants
#define BATCH 4
#define SEQ   4096
#define CDIM  1024
#define NH    16
#define HS    64
#define NL    64
#define MROWS (BATCH*SEQ)        // 16384
#define N3    (3*CDIM)           // 3072

// ---------------- fp32 tiled GEMM: C = A(MxK) @ B(KxN) ----------------
// mode 0: plain store to C0 (row-major MxN)
// mode 1: qkv split epilogue into (B,nh,T,hs) layout q/k/v buffers
__global__ __launch_bounds__(256) void gemm64(const float* __restrict__ A,
                                              const float* __restrict__ B,
                                              float* __restrict__ C0,
                                              float* __restrict__ Cq,
                                              float* __restrict__ Ck,
                                              float* __restrict__ Cv,
                                              int M, int N, int K, int mode)
{
    __shared__ float As[16][64 + 1];
    __shared__ float Bs[16][64 + 1];
    int tid = threadIdx.x;
    int bx = blockIdx.x, by = blockIdx.y;
    int m0 = by * 64, n0 = bx * 64;
    int ty = tid >> 4, tx = tid & 15;
    float acc[4][4] = {};
    const float* Ap = A + (size_t)m0 * K;
    const float* Bp = B + n0;
    int la_r = tid >> 4, la_c = tid & 15;   // A: 16 rows x 16 k per pass
    int lb_r = tid >> 6, lb_c = tid & 63;   // B: 4 k-rows x 64 n per pass

    for (int k0 = 0; k0 < K; k0 += 16) {
        for (int r = 0; r < 4; r++)
            As[la_c][la_r + r * 16] = Ap[(size_t)(la_r + r * 16) * K + k0 + la_c];
        for (int r = 0; r < 4; r++)
            Bs[lb_r + r * 4][lb_c] = Bp[(size_t)(k0 + lb_r + r * 4) * N + lb_c];
        __syncthreads();
        for (int kk = 0; kk < 16; kk++) {
            float a[4], b[4];
            #pragma unroll
            for (int i = 0; i < 4; i++) a[i] = As[kk][ty * 4 + i];
            #pragma unroll
            for (int j = 0; j < 4; j++) b[j] = Bs[kk][tx * 4 + j];
            #pragma unroll
            for (int i = 0; i < 4; i++)
                #pragma unroll
                for (int j = 0; j < 4; j++) acc[i][j] += a[i] * b[j];
        }
        __syncthreads();
    }

    if (mode == 0) {
        for (int i = 0; i < 4; i++)
            for (int j = 0; j < 4; j++)
                C0[(size_t)(m0 + ty * 4 + i) * N + n0 + tx * 4 + j] = acc[i][j];
    } else {
        for (int i = 0; i < 4; i++) {
            int m = m0 + ty * 4 + i;
            int b = m >> 12, t = m & 4095;
            for (int j = 0; j < 4; j++) {
                int n = n0 + tx * 4 + j;
                float* dst; int nn;
                if (n < 1024)      { dst = Cq; nn = n; }
                else if (n < 2048) { dst = Ck; nn = n - 1024; }
                else               { dst = Cv; nn = n - 2048; }
                int h = nn >> 6, d = nn & 63;
                dst[(((size_t)(b * NH + h)) * SEQ + t) * HS + d] = acc[i][j];
            }
        }
    }
}

// ---------------- landmarks: mean-pool T into NL segments ----------------
__global__ __launch_bounds__(256) void landmark_kernel(const float* __restrict__ q,
                                                       const float* __restrict__ k,
                                                       float* __restrict__ ql,
                                                       float* __restrict__ kl)
{
    int idx = blockIdx.x * 256 + threadIdx.x;   // 64bh * 64l * 64d = 262144
    int d = idx & 63, l = (idx >> 6) & 63, bh = idx >> 12;
    const float* qp = q + (((size_t)bh * SEQ) + l * 64) * HS + d;
    const float* kp = k + (((size_t)bh * SEQ) + l * 64) * HS + d;
    float sq = 0.f, sk = 0.f;
    for (int t = 0; t < 64; t++) { sq += qp[t * HS]; sk += kp[t * HS]; }
    ql[idx] = sq * (1.0f / 64.0f);
    kl[idx] = sk * (1.0f / 64.0f);
}

// ---------------- per-(b,h): A = softmax(ql @ kl^T), P = NS-pinv(A) ----------------
// All state in LDS (5 padded 64x65 tiles = 83 KB). A never touches global.
__global__ __launch_bounds__(256) void pinv_kernel(const float* __restrict__ ql,
                                                   const float* __restrict__ kl,
                                                   float* __restrict__ Pbuf)
{
    int bh = blockIdx.x;
    __shared__ float Asm[64][65], V[64][65], KV[64][65], Tb[64][65], Ub[64][65];
    __shared__ float denom_s;
    int tid = threadIdx.x;
    int r = tid >> 2, c0 = (tid & 3) << 4;
    const float* qlp = ql + (size_t)bh * 4096;
    const float* klp = kl + (size_t)bh * 4096;

    // S = ql @ kl^T into Tb
    for (int j = 0; j < 16; j++) {
        int cc = c0 + j; float acc = 0.f;
        for (int d = 0; d < 64; d++) acc += qlp[r * 64 + d] * klp[cc * 64 + d];
        Tb[r][cc] = acc;
    }
    __syncthreads();
    // row softmax -> Asm
    {
        float m = -1e30f;
        for (int j = 0; j < 64; j++) m = fmaxf(m, Tb[r][j]);
        float s = 0.f;
        for (int j = 0; j < 64; j++) s += expf(Tb[r][j] - m);
        float inv = 1.0f / s;
        for (int j = 0; j < 16; j++) {
            int cc = c0 + j;
            Asm[r][cc] = expf(Tb[r][cc] - m) * inv;
        }
    }
    __syncthreads();
    // denom = max over columns of column sums
    if (tid < 64) {
        float cs = 0.f;
        for (int i = 0; i < 64; i++) cs += Asm[i][tid];
        Ub[0][tid] = cs;
    }
    __syncthreads();
    if (tid == 0) {
        float mx = Ub[0][0];
        for (int j = 1; j < 64; j++) mx = fmaxf(mx, Ub[0][j]);
        denom_s = mx;
    }
    __syncthreads();
    // V0 = A^T / denom
    for (int j = 0; j < 16; j++) { int cc = c0 + j; V[r][cc] = Asm[cc][r] / denom_s; }
    __syncthreads();

    float facc[16];
    for (int it = 0; it < 6; it++) {
        // KV = A @ V
        for (int j = 0; j < 16; j++) facc[j] = 0.f;
        for (int kx = 0; kx < 64; kx++) {
            float a = Asm[r][kx];
            for (int j = 0; j < 16; j++) facc[j] += a * V[kx][c0 + j];
        }
        for (int j = 0; j < 16; j++) KV[r][c0 + j] = facc[j];
        __syncthreads();
        // Tb = 7I - KV
        for (int j = 0; j < 16; j++) {
            int cc = c0 + j;
            Tb[r][cc] = (r == cc ? 7.0f : 0.0f) - KV[r][cc];
        }
        __syncthreads();
        // Ub = KV @ Tb
        for (int j = 0; j < 16; j++) facc[j] = 0.f;
        for (int kx = 0; kx < 64; kx++) {
            float a = KV[r][kx];
            for (int j = 0; j < 16; j++) facc[j] += a * Tb[kx][c0 + j];
        }
        for (int j = 0; j < 16; j++) Ub[r][c0 + j] = facc[j];
        __syncthreads();
        // Tb = 15I - Ub
        for (int j = 0; j < 16; j++) {
            int cc = c0 + j;
            Tb[r][cc] = (r == cc ? 15.0f : 0.0f) - Ub[r][cc];
        }
        __syncthreads();
        // Ub = KV @ Tb
        for (int j = 0; j < 16; j++) facc[j] = 0.f;
        for (int kx = 0; kx < 64; kx++) {
            float a = KV[r][kx];
            for (int j = 0; j < 16; j++) facc[j] += a * Tb[kx][c0 + j];
        }
        for (int j = 0; j < 16; j++) Ub[r][c0 + j] = facc[j];
        __syncthreads();
        // Tb = 13I - Ub
        for (int j = 0; j < 16; j++) {
            int cc = c0 + j;
            Tb[r][cc] = (r == cc ? 13.0f : 0.0f) - Ub[r][cc];
        }
        __syncthreads();
        // Ub = V @ Tb ; V = 0.25*Ub
        for (int j = 0; j < 16; j++) facc[j] = 0.f;
        for (int kx = 0; kx < 64; kx++) {
            float a = V[r][kx];
            for (int j = 0; j < 16; j++) facc[j] += a * Tb[kx][c0 + j];
        }
        for (int j = 0; j < 16; j++) Ub[r][c0 + j] = facc[j];
        __syncthreads();
        for (int j = 0; j < 16; j++) V[r][c0 + j] = 0.25f * Ub[r][c0 + j];
        __syncthreads();
    }
    for (int j = 0; j < 16; j++)
        Pbuf[(size_t)bh * 4096 + r * 64 + c0 + j] = V[r][c0 + j];
}

// ---------------- fused N path: Nv[bh] = softmax_rows(ql @ k^T) @ v ----------------
// Online softmax over T=4096 in 64-wide chunks; Sn never materialized.
// grid (16, 64): block handles 4 landmark rows of one bh. thread = (lr=tid>>6, d=tid&63).
__global__ __launch_bounds__(256) void fused_nv(const float* __restrict__ ql,
                                                const float* __restrict__ k,
                                                const float* __restrict__ v,
                                                float* __restrict__ Nv)
{
    int bh = blockIdx.y;
    int l0 = blockIdx.x * 4;
    int tid = threadIdx.x;
    int lr = tid >> 6;          // local landmark row 0..3
    int d  = tid & 63;          // head-dim column (and t index for score calc)
    __shared__ float kch[64][65];   // [t][d]
    __shared__ float vch[64][65];
    __shared__ float qlb[4][64];
    __shared__ float sblk[4][65];   // raw scores
    __shared__ float pblk[4][65];   // exp probs

    qlb[lr][d] = ql[(size_t)bh * 4096 + (l0 + lr) * 64 + d];

    float m = -1e30f, sum = 0.f, acc = 0.f;
    for (int c = 0; c < 64; c++) {
        __syncthreads();
        const float* kp = k + ((size_t)bh * SEQ + c * 64) * HS;
        const float* vp = v + ((size_t)bh * SEQ + c * 64) * HS;
        for (int i = tid; i < 4096; i += 256) {
            kch[i >> 6][i & 63] = kp[i];
            vch[i >> 6][i & 63] = vp[i];
        }
        __syncthreads();
        // score s[lr][t=d] = ql[l0+lr] . k[c*64+d]
        float s = 0.f;
        #pragma unroll 8
        for (int dd = 0; dd < 64; dd++) s += qlb[lr][dd] * kch[d][dd];
        sblk[lr][d] = s;
        __syncthreads();
        // row max of this chunk
        float cm = -1e30f;
        for (int t = 0; t < 64; t++) cm = fmaxf(cm, sblk[lr][t]);
        float mnew = fmaxf(m, cm);
        float alpha = expf(m - mnew);
        pblk[lr][d] = expf(s - mnew);
        __syncthreads();
        float psum = 0.f, a = 0.f;
        for (int t = 0; t < 64; t++) {
            float p = pblk[lr][t];
            psum += p;
            a += p * vch[t][d];
        }
        sum = sum * alpha + psum;
        acc = acc * alpha + a;
        m = mnew;
    }
    Nv[(size_t)bh * 4096 + (l0 + lr) * 64 + d] = acc / sum;
}

// ---------------- PNv[bh] = P[bh] @ Nv[bh] (64x64 each) ----------------
__global__ __launch_bounds__(256) void pnv_kernel(const float* __restrict__ P,
                                                  const float* __restrict__ Nv,
                                                  float* __restrict__ PNv)
{
    int bh = blockIdx.x, tid = threadIdx.x;
    __shared__ float pb[64][65], nb[64][65];
    for (int i = tid; i < 4096; i += 256) {
        pb[i >> 6][i & 63] = P[(size_t)bh * 4096 + i];
        nb[i >> 6][i & 63] = Nv[(size_t)bh * 4096 + i];
    }
    __syncthreads();
    int r = tid >> 2, c0 = (tid & 3) << 4;
    for (int j = 0; j < 16; j++) {
        int cc = c0 + j; float acc = 0.f;
        for (int kx = 0; kx < 64; kx++) acc += pb[r][kx] * nb[kx][cc];
        PNv[(size_t)bh * 4096 + r * 64 + cc] = acc;
    }
}

// ---------------- y = softmax(q @ kl^T) @ PNv, written in (B,T,C) ----------------
__global__ __launch_bounds__(256) void y_kernel(const float* __restrict__ q,
                                                const float* __restrict__ kl,
                                                const float* __restrict__ PNv,
                                                float* __restrict__ yws)
{
    int bh = blockIdx.y;
    int t0 = blockIdx.x * 64;
    int tid = threadIdx.x;
    __shared__ float qch[64][65], klb[64][65], pnv[64][65], srow[64][65];
    const float* qp = q + ((size_t)bh * SEQ + t0) * HS;
    for (int i = tid; i < 4096; i += 256) {
        qch[i >> 6][i & 63] = qp[i];
        klb[i >> 6][i & 63] = kl[(size_t)bh * 4096 + i];
        pnv[i >> 6][i & 63] = PNv[(size_t)bh * 4096 + i];
    }
    __syncthreads();
    int t = tid >> 2, l0 = (tid & 3) << 4;
    for (int j = 0; j < 16; j++) {
        int l = l0 + j; float acc = 0.f;
        for (int d = 0; d < 64; d++) acc += qch[t][d] * klb[l][d];
        srow[t][l] = acc;
    }
    __syncthreads();
    float m = -1e30f;
    for (int l = 0; l < 64; l++) m = fmaxf(m, srow[t][l]);
    float s = 0.f;
    for (int l = 0; l < 64; l++) s += expf(srow[t][l] - m);
    float inv = 1.0f / s;
    int d0 = (tid & 3) << 4;
    float acc[16] = {};
    for (int l = 0; l < 64; l++) {
        float w = expf(srow[t][l] - m) * inv;
        for (int j = 0; j < 16; j++) acc[j] += w * pnv[l][d0 + j];
    }
    int b = bh >> 4, h = bh & 15;
    float* yp = yws + ((size_t)(b * SEQ) + t0 + t) * CDIM + h * HS + d0;
    for (int j = 0; j < 16; j++) yp[j] = acc[j];
}

// ---------------- launch ----------------
extern "C" void kernel_launch(void* const* d_in, const int* in_sizes, int n_in,
                              void* d_out, int out_size, void* d_ws, size_t ws_size,
                              hipStream_t stream)
{
    const float* x  = (const float*)d_in[0];
    const float* Wa = (const float*)d_in[1];
    const float* Wp = (const float*)d_in[2];
    float* out = (float*)d_out;
    float* W = (float*)d_ws;

    // workspace layout (float offsets). y aliases v (v dead before y written).
    const size_t off_q   = 0;
    const size_t off_k   = 16777216;
    const size_t off_v   = 33554432;
    const size_t off_ql  = 50331648;
    const size_t off_kl  = off_ql + 262144;
    const size_t off_P   = off_kl + 262144;
    const size_t off_Nv  = off_P  + 262144;
    const size_t off_PNv = off_Nv + 262144;
    const size_t need = (off_PNv + 262144) * sizeof(float);   // ~206.6 MB
    if (ws_size < need) {
        fprintf(stderr, "[nystrom] ws too small: have %zu need %zu\n", ws_size, need);
        return;
    }

    float* q   = W + off_q;
    float* k   = W + off_k;
    float* v   = W + off_v;
    float* ql  = W + off_ql;
    float* kl  = W + off_kl;
    float* P   = W + off_P;
    float* Nv  = W + off_Nv;
    float* PNv = W + off_PNv;
    float* yws = W + off_v;      // alias: v dead after fused_nv

    // 1) qkv = x @ W_attn, split to q/k/v head-major
    gemm64<<<dim3(N3 / 64, MROWS / 64), 256, 0, stream>>>(x, Wa, nullptr, q, k, v,
                                                          MROWS, N3, CDIM, 1);
    // 2) landmarks
    landmark_kernel<<<262144 / 256, 256, 0, stream>>>(q, k, ql, kl);
    // 3) A + Newton-Schulz pinv (all-LDS)
    pinv_kernel<<<64, 256, 0, stream>>>(ql, kl, P);
    // 4) fused N-scores + online softmax + @v
    fused_nv<<<dim3(16, 64), 256, 0, stream>>>(ql, k, v, Nv);
    // 5) PNv, then fused L-softmax @ PNv -> y (B,T,C)
    pnv_kernel<<<64, 256, 0, stream>>>(P, Nv, PNv);
    y_kernel<<<dim3(64, 64), 256, 0, stream>>>(q, kl, PNv, yws);
    // 6) out = y @ W_proj
    gemm64<<<dim3(CDIM / 64, MROWS / 64), 256, 0, stream>>>(yws, Wp, out, nullptr, nullptr, nullptr,
                                                            MROWS, CDIM, CDIM, 0);
}

// Round 3
// 1539.391 us; speedup vs baseline: 2.2620x; 2.2620x over previous
//
#include <hip/hip_runtime.h>
#include <hip/hip_bf16.h>
#include <cstdio>

#define BATCH 4
#define SEQ   4096
#define CDIM  1024
#define NH    16
#define HS    64
#define NL    64
#define MROWS 16384
#define N3    3072
#define KDIM  1024

typedef __bf16 bf16_t;
typedef bf16_t bf16x8 __attribute__((ext_vector_type(8)));
typedef float  f32x4  __attribute__((ext_vector_type(4)));

// ---------- W transpose + hi/lo bf16 split: dst[n][k] = split(src[k][n]) ----------
__global__ __launch_bounds__(256) void transpose_split(const float* __restrict__ src,
                                                       bf16_t* __restrict__ dhi,
                                                       bf16_t* __restrict__ dlo,
                                                       int K, int N)
{
    __shared__ float tile[64][65];
    int n0 = blockIdx.x * 64, k0 = blockIdx.y * 64;
    for (int idx = threadIdx.x; idx < 4096; idx += 256) {
        int rk = idx >> 6, cn = idx & 63;
        tile[rk][cn] = src[(size_t)(k0 + rk) * N + n0 + cn];
    }
    __syncthreads();
    for (int idx = threadIdx.x; idx < 4096; idx += 256) {
        int rn = idx >> 6, ck = idx & 63;
        float v = tile[ck][rn];
        bf16_t hh = (bf16_t)v;
        size_t o = (size_t)(n0 + rn) * K + k0 + ck;
        dhi[o] = hh;
        dlo[o] = (bf16_t)(v - (float)hh);
    }
}

// ---------- MFMA split-bf16 GEMM: C = A(16384xK) @ B^T(NxK), K=1024 ----------
// mode 1: A = fp32 (split on the fly), epilogue scatters qkv head-major
// mode 0: A = precomputed hi/lo bf16, epilogue plain row-major store
__global__ __launch_bounds__(256) void gemm_split(const float* __restrict__ Af,
                                                  const bf16_t* __restrict__ Ahi_g,
                                                  const bf16_t* __restrict__ Alo_g,
                                                  const bf16_t* __restrict__ Bhi,
                                                  const bf16_t* __restrict__ Blo,
                                                  float* __restrict__ C0,
                                                  float* __restrict__ Cq,
                                                  float* __restrict__ Ck,
                                                  float* __restrict__ Cv,
                                                  int N, int mode)
{
    __shared__ __align__(16) bf16_t AsHi[128][32];
    __shared__ __align__(16) bf16_t AsLo[128][32];
    __shared__ __align__(16) bf16_t BsHi[128][32];
    __shared__ __align__(16) bf16_t BsLo[128][32];
    int t = threadIdx.x;
    int m0 = blockIdx.y * 128, n0 = blockIdx.x * 128;
    int r = t >> 1, h = t & 1;          // staging: row 0..127, k-half 0..1
    int lane = t & 63, wv = t >> 6;
    int wr = wv >> 1, wc = wv & 1;       // wave quadrant in 128x128 tile
    int lm = lane & 15, lk = lane >> 4;  // MFMA lane coords

    f32x4 acc[4][4] = {};

    for (int kc = 0; kc < KDIM; kc += 32) {
        __syncthreads();
        int swz = (r >> 1) & 3;
        int g0 = (2 * h) ^ swz, g1 = (2 * h + 1) ^ swz;
        // ---- stage A (rows m0..m0+127, k kc..kc+31) ----
        if (mode == 1) {
            const float* ap = Af + (size_t)(m0 + r) * KDIM + kc + h * 16;
            f32x4 f[4];
            #pragma unroll
            for (int i = 0; i < 4; i++) f[i] = *(const f32x4*)(ap + 4 * i);
            bf16x8 hi0, hi1, lo0, lo1;
            #pragma unroll
            for (int i = 0; i < 8; i++) {
                float v = f[i >> 2][i & 3];
                bf16_t hh = (bf16_t)v;
                hi0[i] = hh; lo0[i] = (bf16_t)(v - (float)hh);
            }
            #pragma unroll
            for (int i = 0; i < 8; i++) {
                float v = f[2 + (i >> 2)][i & 3];
                bf16_t hh = (bf16_t)v;
                hi1[i] = hh; lo1[i] = (bf16_t)(v - (float)hh);
            }
            *(bf16x8*)&AsHi[r][8 * g0] = hi0; *(bf16x8*)&AsHi[r][8 * g1] = hi1;
            *(bf16x8*)&AsLo[r][8 * g0] = lo0; *(bf16x8*)&AsLo[r][8 * g1] = lo1;
        } else {
            const bf16_t* ah = Ahi_g + (size_t)(m0 + r) * KDIM + kc + h * 16;
            const bf16_t* al = Alo_g + (size_t)(m0 + r) * KDIM + kc + h * 16;
            bf16x8 h0 = *(const bf16x8*)ah, h1 = *(const bf16x8*)(ah + 8);
            bf16x8 l0 = *(const bf16x8*)al, l1 = *(const bf16x8*)(al + 8);
            *(bf16x8*)&AsHi[r][8 * g0] = h0; *(bf16x8*)&AsHi[r][8 * g1] = h1;
            *(bf16x8*)&AsLo[r][8 * g0] = l0; *(bf16x8*)&AsLo[r][8 * g1] = l1;
        }
        // ---- stage B (rows n0..n0+127 of B^T) ----
        {
            const bf16_t* bp = Bhi + (size_t)(n0 + r) * KDIM + kc + h * 16;
            const bf16_t* bq = Blo + (size_t)(n0 + r) * KDIM + kc + h * 16;
            bf16x8 h0 = *(const bf16x8*)bp, h1 = *(const bf16x8*)(bp + 8);
            bf16x8 l0 = *(const bf16x8*)bq, l1 = *(const bf16x8*)(bq + 8);
            *(bf16x8*)&BsHi[r][8 * g0] = h0; *(bf16x8*)&BsHi[r][8 * g1] = h1;
            *(bf16x8*)&BsLo[r][8 * g0] = l0; *(bf16x8*)&BsLo[r][8 * g1] = l1;
        }
        __syncthreads();

        bf16x8 ah[4], al[4], bh_[4], bl_[4];
        #pragma unroll
        for (int mt = 0; mt < 4; mt++) {
            int row = wr * 64 + mt * 16 + lm;
            int col = 8 * (lk ^ ((row >> 1) & 3));
            ah[mt] = *(const bf16x8*)&AsHi[row][col];
            al[mt] = *(const bf16x8*)&AsLo[row][col];
        }
        #pragma unroll
        for (int nt = 0; nt < 4; nt++) {
            int row = wc * 64 + nt * 16 + lm;
            int col = 8 * (lk ^ ((row >> 1) & 3));
            bh_[nt] = *(const bf16x8*)&BsHi[row][col];
            bl_[nt] = *(const bf16x8*)&BsLo[row][col];
        }
        #pragma unroll
        for (int mt = 0; mt < 4; mt++)
            #pragma unroll
            for (int nt = 0; nt < 4; nt++) {
                acc[mt][nt] = __builtin_amdgcn_mfma_f32_16x16x32_bf16(ah[mt], bh_[nt], acc[mt][nt], 0, 0, 0);
                acc[mt][nt] = __builtin_amdgcn_mfma_f32_16x16x32_bf16(ah[mt], bl_[nt], acc[mt][nt], 0, 0, 0);
                acc[mt][nt] = __builtin_amdgcn_mfma_f32_16x16x32_bf16(al[mt], bh_[nt], acc[mt][nt], 0, 0, 0);
            }
    }

    if (mode == 0) {
        #pragma unroll
        for (int mt = 0; mt < 4; mt++) {
            int grow0 = m0 + wr * 64 + mt * 16 + lk * 4;
            #pragma unroll
            for (int nt = 0; nt < 4; nt++) {
                int gcol = n0 + wc * 64 + nt * 16 + lm;
                #pragma unroll
                for (int reg = 0; reg < 4; reg++)
                    C0[(size_t)(grow0 + reg) * N + gcol] = acc[mt][nt][reg];
            }
        }
    } else {
        #pragma unroll
        for (int mt = 0; mt < 4; mt++) {
            int grow0 = m0 + wr * 64 + mt * 16 + lk * 4;
            #pragma unroll
            for (int nt = 0; nt < 4; nt++) {
                int n = n0 + wc * 64 + nt * 16 + lm;
                float* dst; int nn;
                if (n < 1024)      { dst = Cq; nn = n; }
                else if (n < 2048) { dst = Ck; nn = n - 1024; }
                else               { dst = Cv; nn = n - 2048; }
                int hh = nn >> 6, d = nn & 63;
                #pragma unroll
                for (int reg = 0; reg < 4; reg++) {
                    int m = grow0 + reg;
                    int b = m >> 12, tt = m & 4095;
                    dst[(((size_t)(b * NH + hh)) * SEQ + tt) * HS + d] = acc[mt][nt][reg];
                }
            }
        }
    }
}

// ---------------- landmarks ----------------
__global__ __launch_bounds__(256) void landmark_kernel(const float* __restrict__ q,
                                                       const float* __restrict__ k,
                                                       float* __restrict__ ql,
                                                       float* __restrict__ kl)
{
    int idx = blockIdx.x * 256 + threadIdx.x;
    int d = idx & 63, l = (idx >> 6) & 63, bh = idx >> 12;
    const float* qp = q + (((size_t)bh * SEQ) + l * 64) * HS + d;
    const float* kp = k + (((size_t)bh * SEQ) + l * 64) * HS + d;
    float sq = 0.f, sk = 0.f;
    for (int t = 0; t < 64; t++) { sq += qp[t * HS]; sk += kp[t * HS]; }
    ql[idx] = sq * (1.0f / 64.0f);
    kl[idx] = sk * (1.0f / 64.0f);
}

// ---------------- pinv (all-LDS Newton-Schulz) ----------------
__global__ __launch_bounds__(256) void pinv_kernel(const float* __restrict__ ql,
                                                   const float* __restrict__ kl,
                                                   float* __restrict__ Pbuf)
{
    int bh = blockIdx.x;
    __shared__ float Asm[64][65], V[64][65], KV[64][65], Tb[64][65], Ub[64][65];
    __shared__ float denom_s;
    int tid = threadIdx.x;
    int r = tid >> 2, c0 = (tid & 3) << 4;
    const float* qlp = ql + (size_t)bh * 4096;
    const float* klp = kl + (size_t)bh * 4096;

    for (int j = 0; j < 16; j++) {
        int cc = c0 + j; float acc = 0.f;
        for (int d = 0; d < 64; d++) acc += qlp[r * 64 + d] * klp[cc * 64 + d];
        Tb[r][cc] = acc;
    }
    __syncthreads();
    {
        float m = -1e30f;
        for (int j = 0; j < 64; j++) m = fmaxf(m, Tb[r][j]);
        float s = 0.f;
        for (int j = 0; j < 64; j++) s += expf(Tb[r][j] - m);
        float inv = 1.0f / s;
        for (int j = 0; j < 16; j++) {
            int cc = c0 + j;
            Asm[r][cc] = expf(Tb[r][cc] - m) * inv;
        }
    }
    __syncthreads();
    if (tid < 64) {
        float cs = 0.f;
        for (int i = 0; i < 64; i++) cs += Asm[i][tid];
        Ub[0][tid] = cs;
    }
    __syncthreads();
    if (tid == 0) {
        float mx = Ub[0][0];
        for (int j = 1; j < 64; j++) mx = fmaxf(mx, Ub[0][j]);
        denom_s = mx;
    }
    __syncthreads();
    for (int j = 0; j < 16; j++) { int cc = c0 + j; V[r][cc] = Asm[cc][r] / denom_s; }
    __syncthreads();

    float facc[16];
    for (int it = 0; it < 6; it++) {
        for (int j = 0; j < 16; j++) facc[j] = 0.f;
        for (int kx = 0; kx < 64; kx++) {
            float a = Asm[r][kx];
            for (int j = 0; j < 16; j++) facc[j] += a * V[kx][c0 + j];
        }
        for (int j = 0; j < 16; j++) KV[r][c0 + j] = facc[j];
        __syncthreads();
        for (int j = 0; j < 16; j++) {
            int cc = c0 + j;
            Tb[r][cc] = (r == cc ? 7.0f : 0.0f) - KV[r][cc];
        }
        __syncthreads();
        for (int j = 0; j < 16; j++) facc[j] = 0.f;
        for (int kx = 0; kx < 64; kx++) {
            float a = KV[r][kx];
            for (int j = 0; j < 16; j++) facc[j] += a * Tb[kx][c0 + j];
        }
        for (int j = 0; j < 16; j++) Ub[r][c0 + j] = facc[j];
        __syncthreads();
        for (int j = 0; j < 16; j++) {
            int cc = c0 + j;
            Tb[r][cc] = (r == cc ? 15.0f : 0.0f) - Ub[r][cc];
        }
        __syncthreads();
        for (int j = 0; j < 16; j++) facc[j] = 0.f;
        for (int kx = 0; kx < 64; kx++) {
            float a = KV[r][kx];
            for (int j = 0; j < 16; j++) facc[j] += a * Tb[kx][c0 + j];
        }
        for (int j = 0; j < 16; j++) Ub[r][c0 + j] = facc[j];
        __syncthreads();
        for (int j = 0; j < 16; j++) {
            int cc = c0 + j;
            Tb[r][cc] = (r == cc ? 13.0f : 0.0f) - Ub[r][cc];
        }
        __syncthreads();
        for (int j = 0; j < 16; j++) facc[j] = 0.f;
        for (int kx = 0; kx < 64; kx++) {
            float a = V[r][kx];
            for (int j = 0; j < 16; j++) facc[j] += a * Tb[kx][c0 + j];
        }
        for (int j = 0; j < 16; j++) Ub[r][c0 + j] = facc[j];
        __syncthreads();
        for (int j = 0; j < 16; j++) V[r][c0 + j] = 0.25f * Ub[r][c0 + j];
        __syncthreads();
    }
    for (int j = 0; j < 16; j++)
        Pbuf[(size_t)bh * 4096 + r * 64 + c0 + j] = V[r][c0 + j];
}

// ---------------- fused N path: 16 landmark rows per block ----------------
__global__ __launch_bounds__(256) void fused_nv(const float* __restrict__ ql,
                                                const float* __restrict__ k,
                                                const float* __restrict__ v,
                                                float* __restrict__ Nv)
{
    int bh = blockIdx.y;
    int l0 = blockIdx.x * 16;
    int tid = threadIdx.x;
    int lr = tid >> 6;
    int d  = tid & 63;
    __shared__ float kch[64][65];
    __shared__ float vch[64][65];
    __shared__ float qlb[16][64];
    __shared__ float sblk[16][65];
    __shared__ float pblk[16][65];

    for (int idx = tid; idx < 1024; idx += 256) {
        int rr = idx >> 6, cc = idx & 63;
        qlb[rr][cc] = ql[(size_t)bh * 4096 + (l0 + rr) * 64 + cc];
    }

    float mrow[4], srow[4], arow[4];
    #pragma unroll
    for (int rr = 0; rr < 4; rr++) { mrow[rr] = -1e30f; srow[rr] = 0.f; arow[rr] = 0.f; }

    for (int c = 0; c < 64; c++) {
        __syncthreads();
        const float* kp = k + ((size_t)bh * SEQ + c * 64) * HS;
        const float* vp = v + ((size_t)bh * SEQ + c * 64) * HS;
        for (int i = tid; i < 4096; i += 256) {
            kch[i >> 6][i & 63] = kp[i];
            vch[i >> 6][i & 63] = vp[i];
        }
        __syncthreads();
        float sc[4];
        #pragma unroll
        for (int rr = 0; rr < 4; rr++) {
            int rl = lr + rr * 4;
            float s = 0.f;
            #pragma unroll 8
            for (int dd = 0; dd < 64; dd++) s += qlb[rl][dd] * kch[d][dd];
            sc[rr] = s;
            sblk[rl][d] = s;
        }
        __syncthreads();
        float alpha[4];
        #pragma unroll
        for (int rr = 0; rr < 4; rr++) {
            int rl = lr + rr * 4;
            float cm = -1e30f;
            for (int t2 = 0; t2 < 64; t2++) cm = fmaxf(cm, sblk[rl][t2]);
            float mnew = fmaxf(mrow[rr], cm);
            alpha[rr] = expf(mrow[rr] - mnew);
            pblk[rl][d] = expf(sc[rr] - mnew);
            mrow[rr] = mnew;
        }
        __syncthreads();
        #pragma unroll
        for (int rr = 0; rr < 4; rr++) {
            int rl = lr + rr * 4;
            float psum = 0.f, a = 0.f;
            for (int t2 = 0; t2 < 64; t2++) {
                float p = pblk[rl][t2];
                psum += p;
                a += p * vch[t2][d];
            }
            srow[rr] = srow[rr] * alpha[rr] + psum;
            arow[rr] = arow[rr] * alpha[rr] + a;
        }
    }
    for (int rr = 0; rr < 4; rr++)
        Nv[(size_t)bh * 4096 + (l0 + lr + rr * 4) * 64 + d] = arow[rr] / srow[rr];
}

// ---------------- PNv = P @ Nv ----------------
__global__ __launch_bounds__(256) void pnv_kernel(const float* __restrict__ P,
                                                  const float* __restrict__ Nv,
                                                  float* __restrict__ PNv)
{
    int bh = blockIdx.x, tid = threadIdx.x;
    __shared__ float pb[64][65], nb[64][65];
    for (int i = tid; i < 4096; i += 256) {
        pb[i >> 6][i & 63] = P[(size_t)bh * 4096 + i];
        nb[i >> 6][i & 63] = Nv[(size_t)bh * 4096 + i];
    }
    __syncthreads();
    int r = tid >> 2, c0 = (tid & 3) << 4;
    for (int j = 0; j < 16; j++) {
        int cc = c0 + j; float acc = 0.f;
        for (int kx = 0; kx < 64; kx++) acc += pb[r][kx] * nb[kx][cc];
        PNv[(size_t)bh * 4096 + r * 64 + cc] = acc;
    }
}

// ---------------- y = softmax(q @ kl^T) @ PNv -> hi/lo bf16 (B,T,C) ----------------
__global__ __launch_bounds__(256) void y_kernel(const float* __restrict__ q,
                                                const float* __restrict__ kl,
                                                const float* __restrict__ PNv,
                                                bf16_t* __restrict__ yhi,
                                                bf16_t* __restrict__ ylo)
{
    int bh = blockIdx.y;
    int t0 = blockIdx.x * 64;
    int tid = threadIdx.x;
    __shared__ float qch[64][65], klb[64][65], pnv[64][65], srow[64][65];
    const float* qp = q + ((size_t)bh * SEQ + t0) * HS;
    for (int i = tid; i < 4096; i += 256) {
        qch[i >> 6][i & 63] = qp[i];
        klb[i >> 6][i & 63] = kl[(size_t)bh * 4096 + i];
        pnv[i >> 6][i & 63] = PNv[(size_t)bh * 4096 + i];
    }
    __syncthreads();
    int t = tid >> 2, l0 = (tid & 3) << 4;
    for (int j = 0; j < 16; j++) {
        int l = l0 + j; float acc = 0.f;
        for (int d = 0; d < 64; d++) acc += qch[t][d] * klb[l][d];
        srow[t][l] = acc;
    }
    __syncthreads();
    float m = -1e30f;
    for (int l = 0; l < 64; l++) m = fmaxf(m, srow[t][l]);
    float s = 0.f;
    for (int l = 0; l < 64; l++) s += expf(srow[t][l] - m);
    float inv = 1.0f / s;
    int d0 = (tid & 3) << 4;
    float acc[16] = {};
    for (int l = 0; l < 64; l++) {
        float w = expf(srow[t][l] - m) * inv;
        for (int j = 0; j < 16; j++) acc[j] += w * pnv[l][d0 + j];
    }
    int b = bh >> 4, h = bh & 15;
    size_t o = ((size_t)(b * SEQ) + t0 + t) * CDIM + h * HS + d0;
    for (int j = 0; j < 16; j++) {
        float v = acc[j];
        bf16_t hh = (bf16_t)v;
        yhi[o + j] = hh;
        ylo[o + j] = (bf16_t)(v - (float)hh);
    }
}

// ---------------- launch ----------------
extern "C" void kernel_launch(void* const* d_in, const int* in_sizes, int n_in,
                              void* d_out, int out_size, void* d_ws, size_t ws_size,
                              hipStream_t stream)
{
    const float* x  = (const float*)d_in[0];
    const float* Wa = (const float*)d_in[1];
    const float* Wp = (const float*)d_in[2];
    float* out = (float*)d_out;
    float* W = (float*)d_ws;

    // float-slot offsets
    const size_t off_q   = 0;
    const size_t off_k   = 16777216;
    const size_t off_v   = 33554432;
    const size_t off_ql  = 50331648;
    const size_t off_kl  = off_ql + 262144;
    const size_t off_P   = off_kl + 262144;
    const size_t off_Nv  = off_P  + 262144;
    const size_t off_PNv = off_Nv + 262144;
    const size_t off_WatH = off_PNv + 262144;           // 3072*1024 bf16 = 1572864 slots
    const size_t off_WatL = off_WatH + 1572864;
    const size_t off_WptH = off_WatL + 1572864;         // 1024*1024 bf16 = 524288 slots
    const size_t off_WptL = off_WptH + 524288;
    const size_t need = (off_WptL + 524288) * sizeof(float);   // ~223 MB
    if (ws_size < need) {
        fprintf(stderr, "[nystrom] ws too small: have %zu need %zu\n", ws_size, need);
        return;
    }

    float* q   = W + off_q;
    float* k   = W + off_k;
    float* v   = W + off_v;
    float* ql  = W + off_ql;
    float* kl  = W + off_kl;
    float* P   = W + off_P;
    float* Nv  = W + off_Nv;
    float* PNv = W + off_PNv;
    bf16_t* WatH = (bf16_t*)(W + off_WatH);
    bf16_t* WatL = (bf16_t*)(W + off_WatL);
    bf16_t* WptH = (bf16_t*)(W + off_WptH);
    bf16_t* WptL = (bf16_t*)(W + off_WptL);
    // y hi/lo alias k (dead after fused_nv): exactly 64 MiB
    bf16_t* yhi = (bf16_t*)(W + off_k);
    bf16_t* ylo = yhi + (size_t)MROWS * CDIM;

    // 0) weight transpose + split
    transpose_split<<<dim3(N3 / 64, KDIM / 64), 256, 0, stream>>>(Wa, WatH, WatL, KDIM, N3);
    transpose_split<<<dim3(CDIM / 64, KDIM / 64), 256, 0, stream>>>(Wp, WptH, WptL, KDIM, CDIM);
    // 1) qkv = x @ W_attn (MFMA split), scatter to q/k/v head-major
    gemm_split<<<dim3(N3 / 128, MROWS / 128), 256, 0, stream>>>(x, nullptr, nullptr,
                                                                WatH, WatL,
                                                                nullptr, q, k, v, N3, 1);
    // 2) landmarks
    landmark_kernel<<<262144 / 256, 256, 0, stream>>>(q, k, ql, kl);
    // 3) Newton-Schulz pinv
    pinv_kernel<<<64, 256, 0, stream>>>(ql, kl, P);
    // 4) fused N-scores + online softmax + @v
    fused_nv<<<dim3(4, 64), 256, 0, stream>>>(ql, k, v, Nv);
    // 5) P @ Nv, then fused L-softmax @ PNv -> y (bf16 hi/lo, aliases k)
    pnv_kernel<<<64, 256, 0, stream>>>(P, Nv, PNv);
    y_kernel<<<dim3(64, 64), 256, 0, stream>>>(q, kl, PNv, yhi, ylo);
    // 6) out = y @ W_proj (MFMA split)
    gemm_split<<<dim3(CDIM / 128, MROWS / 128), 256, 0, stream>>>(nullptr, yhi, ylo,
                                                                  WptH, WptL,
                                                                  out, nullptr, nullptr, nullptr, CDIM, 0);
}

// Round 4
// 1121.143 us; speedup vs baseline: 3.1059x; 1.3731x over previous
//
#include <hip/hip_runtime.h>
#include <hip/hip_bf16.h>
#include <cstdio>

#define BATCH 4
#define SEQ   4096
#define CDIM  1024
#define NH    16
#define HS    64
#define NL    64
#define MROWS 16384
#define N3    3072
#define KDIM  1024

typedef __bf16 bf16_t;
typedef bf16_t bf16x8 __attribute__((ext_vector_type(8)));
typedef float  f32x4  __attribute__((ext_vector_type(4)));

// ---------- W transpose + hi/lo bf16 split: dst[n][k] = split(src[k][n]) ----------
__global__ __launch_bounds__(256) void transpose_split(const float* __restrict__ src,
                                                       bf16_t* __restrict__ dhi,
                                                       bf16_t* __restrict__ dlo,
                                                       int K, int N)
{
    __shared__ float tile[64][65];
    int n0 = blockIdx.x * 64, k0 = blockIdx.y * 64;
    for (int idx = threadIdx.x; idx < 4096; idx += 256) {
        int rk = idx >> 6, cn = idx & 63;
        tile[rk][cn] = src[(size_t)(k0 + rk) * N + n0 + cn];
    }
    __syncthreads();
    for (int idx = threadIdx.x; idx < 4096; idx += 256) {
        int rn = idx >> 6, ck = idx & 63;
        float v = tile[ck][rn];
        bf16_t hh = (bf16_t)v;
        size_t o = (size_t)(n0 + rn) * K + k0 + ck;
        dhi[o] = hh;
        dlo[o] = (bf16_t)(v - (float)hh);
    }
}

// ---------- MFMA split-bf16 GEMM: C = A(16384xK) @ B^T(NxK), K=1024 ----------
__global__ __launch_bounds__(256) void gemm_split(const float* __restrict__ Af,
                                                  const bf16_t* __restrict__ Ahi_g,
                                                  const bf16_t* __restrict__ Alo_g,
                                                  const bf16_t* __restrict__ Bhi,
                                                  const bf16_t* __restrict__ Blo,
                                                  float* __restrict__ C0,
                                                  float* __restrict__ Cq,
                                                  float* __restrict__ Ck,
                                                  float* __restrict__ Cv,
                                                  int N, int mode)
{
    __shared__ __align__(16) bf16_t AsHi[128][32];
    __shared__ __align__(16) bf16_t AsLo[128][32];
    __shared__ __align__(16) bf16_t BsHi[128][32];
    __shared__ __align__(16) bf16_t BsLo[128][32];
    int t = threadIdx.x;
    int m0 = blockIdx.y * 128, n0 = blockIdx.x * 128;
    int r = t >> 1, h = t & 1;
    int lane = t & 63, wv = t >> 6;
    int wr = wv >> 1, wc = wv & 1;
    int lm = lane & 15, lk = lane >> 4;

    f32x4 acc[4][4] = {};

    for (int kc = 0; kc < KDIM; kc += 32) {
        __syncthreads();
        int swz = (r >> 1) & 3;
        int g0 = (2 * h) ^ swz, g1 = (2 * h + 1) ^ swz;
        if (mode == 1) {
            const float* ap = Af + (size_t)(m0 + r) * KDIM + kc + h * 16;
            f32x4 f[4];
            #pragma unroll
            for (int i = 0; i < 4; i++) f[i] = *(const f32x4*)(ap + 4 * i);
            bf16x8 hi0, hi1, lo0, lo1;
            #pragma unroll
            for (int i = 0; i < 8; i++) {
                float v = f[i >> 2][i & 3];
                bf16_t hh = (bf16_t)v;
                hi0[i] = hh; lo0[i] = (bf16_t)(v - (float)hh);
            }
            #pragma unroll
            for (int i = 0; i < 8; i++) {
                float v = f[2 + (i >> 2)][i & 3];
                bf16_t hh = (bf16_t)v;
                hi1[i] = hh; lo1[i] = (bf16_t)(v - (float)hh);
            }
            *(bf16x8*)&AsHi[r][8 * g0] = hi0; *(bf16x8*)&AsHi[r][8 * g1] = hi1;
            *(bf16x8*)&AsLo[r][8 * g0] = lo0; *(bf16x8*)&AsLo[r][8 * g1] = lo1;
        } else {
            const bf16_t* ah = Ahi_g + (size_t)(m0 + r) * KDIM + kc + h * 16;
            const bf16_t* al = Alo_g + (size_t)(m0 + r) * KDIM + kc + h * 16;
            bf16x8 h0 = *(const bf16x8*)ah, h1 = *(const bf16x8*)(ah + 8);
            bf16x8 l0 = *(const bf16x8*)al, l1 = *(const bf16x8*)(al + 8);
            *(bf16x8*)&AsHi[r][8 * g0] = h0; *(bf16x8*)&AsHi[r][8 * g1] = h1;
            *(bf16x8*)&AsLo[r][8 * g0] = l0; *(bf16x8*)&AsLo[r][8 * g1] = l1;
        }
        {
            const bf16_t* bp = Bhi + (size_t)(n0 + r) * KDIM + kc + h * 16;
            const bf16_t* bq = Blo + (size_t)(n0 + r) * KDIM + kc + h * 16;
            bf16x8 h0 = *(const bf16x8*)bp, h1 = *(const bf16x8*)(bp + 8);
            bf16x8 l0 = *(const bf16x8*)bq, l1 = *(const bf16x8*)(bq + 8);
            *(bf16x8*)&BsHi[r][8 * g0] = h0; *(bf16x8*)&BsHi[r][8 * g1] = h1;
            *(bf16x8*)&BsLo[r][8 * g0] = l0; *(bf16x8*)&BsLo[r][8 * g1] = l1;
        }
        __syncthreads();

        bf16x8 ah[4], al[4], bh_[4], bl_[4];
        #pragma unroll
        for (int mt = 0; mt < 4; mt++) {
            int row = wr * 64 + mt * 16 + lm;
            int col = 8 * (lk ^ ((row >> 1) & 3));
            ah[mt] = *(const bf16x8*)&AsHi[row][col];
            al[mt] = *(const bf16x8*)&AsLo[row][col];
        }
        #pragma unroll
        for (int nt = 0; nt < 4; nt++) {
            int row = wc * 64 + nt * 16 + lm;
            int col = 8 * (lk ^ ((row >> 1) & 3));
            bh_[nt] = *(const bf16x8*)&BsHi[row][col];
            bl_[nt] = *(const bf16x8*)&BsLo[row][col];
        }
        #pragma unroll
        for (int mt = 0; mt < 4; mt++)
            #pragma unroll
            for (int nt = 0; nt < 4; nt++) {
                acc[mt][nt] = __builtin_amdgcn_mfma_f32_16x16x32_bf16(ah[mt], bh_[nt], acc[mt][nt], 0, 0, 0);
                acc[mt][nt] = __builtin_amdgcn_mfma_f32_16x16x32_bf16(ah[mt], bl_[nt], acc[mt][nt], 0, 0, 0);
                acc[mt][nt] = __builtin_amdgcn_mfma_f32_16x16x32_bf16(al[mt], bh_[nt], acc[mt][nt], 0, 0, 0);
            }
    }

    if (mode == 0) {
        #pragma unroll
        for (int mt = 0; mt < 4; mt++) {
            int grow0 = m0 + wr * 64 + mt * 16 + lk * 4;
            #pragma unroll
            for (int nt = 0; nt < 4; nt++) {
                int gcol = n0 + wc * 64 + nt * 16 + lm;
                #pragma unroll
                for (int reg = 0; reg < 4; reg++)
                    C0[(size_t)(grow0 + reg) * N + gcol] = acc[mt][nt][reg];
            }
        }
    } else {
        #pragma unroll
        for (int mt = 0; mt < 4; mt++) {
            int grow0 = m0 + wr * 64 + mt * 16 + lk * 4;
            #pragma unroll
            for (int nt = 0; nt < 4; nt++) {
                int n = n0 + wc * 64 + nt * 16 + lm;
                float* dst; int nn;
                if (n < 1024)      { dst = Cq; nn = n; }
                else if (n < 2048) { dst = Ck; nn = n - 1024; }
                else               { dst = Cv; nn = n - 2048; }
                int hh = nn >> 6, d = nn & 63;
                #pragma unroll
                for (int reg = 0; reg < 4; reg++) {
                    int m = grow0 + reg;
                    int b = m >> 12, tt = m & 4095;
                    dst[(((size_t)(b * NH + hh)) * SEQ + tt) * HS + d] = acc[mt][nt][reg];
                }
            }
        }
    }
}

// ---------------- landmarks ----------------
__global__ __launch_bounds__(256) void landmark_kernel(const float* __restrict__ q,
                                                       const float* __restrict__ k,
                                                       float* __restrict__ ql,
                                                       float* __restrict__ kl)
{
    int idx = blockIdx.x * 256 + threadIdx.x;
    int d = idx & 63, l = (idx >> 6) & 63, bh = idx >> 12;
    const float* qp = q + (((size_t)bh * SEQ) + l * 64) * HS + d;
    const float* kp = k + (((size_t)bh * SEQ) + l * 64) * HS + d;
    float sq = 0.f, sk = 0.f;
    for (int t = 0; t < 64; t++) { sq += qp[t * HS]; sk += kp[t * HS]; }
    ql[idx] = sq * (1.0f / 64.0f);
    kl[idx] = sk * (1.0f / 64.0f);
}

// ---------------- pinv (all-LDS Newton-Schulz) ----------------
__global__ __launch_bounds__(256) void pinv_kernel(const float* __restrict__ ql,
                                                   const float* __restrict__ kl,
                                                   float* __restrict__ Pbuf)
{
    int bh = blockIdx.x;
    __shared__ float Asm[64][65], V[64][65], KV[64][65], Tb[64][65], Ub[64][65];
    __shared__ float denom_s;
    int tid = threadIdx.x;
    int r = tid >> 2, c0 = (tid & 3) << 4;
    const float* qlp = ql + (size_t)bh * 4096;
    const float* klp = kl + (size_t)bh * 4096;

    for (int j = 0; j < 16; j++) {
        int cc = c0 + j; float acc = 0.f;
        for (int d = 0; d < 64; d++) acc += qlp[r * 64 + d] * klp[cc * 64 + d];
        Tb[r][cc] = acc;
    }
    __syncthreads();
    {
        float m = -1e30f;
        for (int j = 0; j < 64; j++) m = fmaxf(m, Tb[r][j]);
        float s = 0.f;
        for (int j = 0; j < 64; j++) s += expf(Tb[r][j] - m);
        float inv = 1.0f / s;
        for (int j = 0; j < 16; j++) {
            int cc = c0 + j;
            Asm[r][cc] = expf(Tb[r][cc] - m) * inv;
        }
    }
    __syncthreads();
    if (tid < 64) {
        float cs = 0.f;
        for (int i = 0; i < 64; i++) cs += Asm[i][tid];
        Ub[0][tid] = cs;
    }
    __syncthreads();
    if (tid == 0) {
        float mx = Ub[0][0];
        for (int j = 1; j < 64; j++) mx = fmaxf(mx, Ub[0][j]);
        denom_s = mx;
    }
    __syncthreads();
    for (int j = 0; j < 16; j++) { int cc = c0 + j; V[r][cc] = Asm[cc][r] / denom_s; }
    __syncthreads();

    float facc[16];
    for (int it = 0; it < 6; it++) {
        for (int j = 0; j < 16; j++) facc[j] = 0.f;
        for (int kx = 0; kx < 64; kx++) {
            float a = Asm[r][kx];
            for (int j = 0; j < 16; j++) facc[j] += a * V[kx][c0 + j];
        }
        for (int j = 0; j < 16; j++) KV[r][c0 + j] = facc[j];
        __syncthreads();
        for (int j = 0; j < 16; j++) {
            int cc = c0 + j;
            Tb[r][cc] = (r == cc ? 7.0f : 0.0f) - KV[r][cc];
        }
        __syncthreads();
        for (int j = 0; j < 16; j++) facc[j] = 0.f;
        for (int kx = 0; kx < 64; kx++) {
            float a = KV[r][kx];
            for (int j = 0; j < 16; j++) facc[j] += a * Tb[kx][c0 + j];
        }
        for (int j = 0; j < 16; j++) Ub[r][c0 + j] = facc[j];
        __syncthreads();
        for (int j = 0; j < 16; j++) {
            int cc = c0 + j;
            Tb[r][cc] = (r == cc ? 15.0f : 0.0f) - Ub[r][cc];
        }
        __syncthreads();
        for (int j = 0; j < 16; j++) facc[j] = 0.f;
        for (int kx = 0; kx < 64; kx++) {
            float a = KV[r][kx];
            for (int j = 0; j < 16; j++) facc[j] += a * Tb[kx][c0 + j];
        }
        for (int j = 0; j < 16; j++) Ub[r][c0 + j] = facc[j];
        __syncthreads();
        for (int j = 0; j < 16; j++) {
            int cc = c0 + j;
            Tb[r][cc] = (r == cc ? 13.0f : 0.0f) - Ub[r][cc];
        }
        __syncthreads();
        for (int j = 0; j < 16; j++) facc[j] = 0.f;
        for (int kx = 0; kx < 64; kx++) {
            float a = V[r][kx];
            for (int j = 0; j < 16; j++) facc[j] += a * Tb[kx][c0 + j];
        }
        for (int j = 0; j < 16; j++) Ub[r][c0 + j] = facc[j];
        __syncthreads();
        for (int j = 0; j < 16; j++) V[r][c0 + j] = 0.25f * Ub[r][c0 + j];
        __syncthreads();
    }
    for (int j = 0; j < 16; j++)
        Pbuf[(size_t)bh * 4096 + r * 64 + c0 + j] = V[r][c0 + j];
}

// ---------------- N path phase 1: per (bh, 256-wide t-chunk) partials ----------------
// thread (rg=tid>>4, tg=tid&15): score tile rows 4rg..+3 x t 4tg..+3 (outer product),
// online (m,l,acc) over 4 sub-chunks of 64 t; acc tile rows 4rg..+3 x d 4tg..+3.
#define NVP 68
__global__ __launch_bounds__(256) void nv_partial(const float* __restrict__ ql,
                                                  const float* __restrict__ k,
                                                  const float* __restrict__ v,
                                                  float* __restrict__ pm,
                                                  float* __restrict__ ps,
                                                  float* __restrict__ pacc)
{
    int bh = blockIdx.y;
    int c0 = blockIdx.x;            // t-chunk: t in [c0*256, c0*256+256)
    int tid = threadIdx.x;
    int rg = tid >> 4, tg = tid & 15;
    __shared__ float qlT[64][NVP];  // [d][l]
    __shared__ float kT[64][NVP];   // [d][t]
    __shared__ float vch[64][NVP];  // [t][d]
    __shared__ float pch[64][NVP];  // [l][t]

    {
        const float* qp = ql + (size_t)bh * 4096;
        for (int i = tid; i < 4096; i += 256) {
            int l = i >> 6, d = i & 63;
            qlT[d][l] = qp[i];
        }
    }

    float m_r[4], s_r[4];
    float acc[4][4];
    #pragma unroll
    for (int i = 0; i < 4; i++) {
        m_r[i] = -1e30f; s_r[i] = 0.f;
        #pragma unroll
        for (int j = 0; j < 4; j++) acc[i][j] = 0.f;
    }

    for (int sc = 0; sc < 4; sc++) {
        __syncthreads();
        const float* kp = k + ((size_t)bh * SEQ + c0 * 256 + sc * 64) * HS;
        const float* vp = v + ((size_t)bh * SEQ + c0 * 256 + sc * 64) * HS;
        for (int i = tid; i < 4096; i += 256) {
            int tt = i >> 6, d = i & 63;
            kT[d][tt]  = kp[i];
            vch[tt][d] = vp[i];
        }
        __syncthreads();

        // 4x4 score tile
        float s[4][4] = {};
        #pragma unroll 4
        for (int dd = 0; dd < 64; dd++) {
            f32x4 a = *(const f32x4*)&qlT[dd][rg * 4];
            f32x4 b = *(const f32x4*)&kT[dd][tg * 4];
            #pragma unroll
            for (int i = 0; i < 4; i++)
                #pragma unroll
                for (int j = 0; j < 4; j++) s[i][j] += a[i] * b[j];
        }

        // per-row online softmax update (rows within one wave: 16-lane groups)
        #pragma unroll
        for (int i = 0; i < 4; i++) {
            float tmax = fmaxf(fmaxf(s[i][0], s[i][1]), fmaxf(s[i][2], s[i][3]));
            #pragma unroll
            for (int off = 1; off < 16; off <<= 1)
                tmax = fmaxf(tmax, __shfl_xor(tmax, off, 64));
            float mnew = fmaxf(m_r[i], tmax);
            float alpha = expf(m_r[i] - mnew);
            m_r[i] = mnew;
            float psum = 0.f;
            #pragma unroll
            for (int j = 0; j < 4; j++) {
                float p = expf(s[i][j] - mnew);
                s[i][j] = p;
                psum += p;
            }
            #pragma unroll
            for (int off = 1; off < 16; off <<= 1)
                psum += __shfl_xor(psum, off, 64);
            s_r[i] = s_r[i] * alpha + psum;
            *(f32x4*)&pch[rg * 4 + i][tg * 4] = *(f32x4*)&s[i][0];
            #pragma unroll
            for (int j = 0; j < 4; j++) acc[i][j] *= alpha;
        }
        __syncthreads();

        // PV: acc[i][j] += sum_t p[row_i][t] * v[t][d_j]
        #pragma unroll 2
        for (int tt = 0; tt < 64; tt++) {
            f32x4 vv = *(const f32x4*)&vch[tt][tg * 4];
            float p0 = pch[rg * 4 + 0][tt];
            float p1 = pch[rg * 4 + 1][tt];
            float p2 = pch[rg * 4 + 2][tt];
            float p3 = pch[rg * 4 + 3][tt];
            #pragma unroll
            for (int j = 0; j < 4; j++) {
                acc[0][j] += p0 * vv[j];
                acc[1][j] += p1 * vv[j];
                acc[2][j] += p2 * vv[j];
                acc[3][j] += p3 * vv[j];
            }
        }
    }

    float* paccp = pacc + ((((size_t)bh * 16 + c0) * 64) + rg * 4) * 64 + tg * 4;
    #pragma unroll
    for (int i = 0; i < 4; i++)
        *(f32x4*)&paccp[(size_t)i * 64] = *(f32x4*)&acc[i][0];
    if (tg == 0) {
        #pragma unroll
        for (int i = 0; i < 4; i++) {
            pm[((size_t)bh * 16 + c0) * 64 + rg * 4 + i] = m_r[i];
            ps[((size_t)bh * 16 + c0) * 64 + rg * 4 + i] = s_r[i];
        }
    }
}

// ---------------- N path phase 2: combine 16 chunk partials ----------------
__global__ __launch_bounds__(256) void nv_combine(const float* __restrict__ pm,
                                                  const float* __restrict__ ps,
                                                  const float* __restrict__ pacc,
                                                  float* __restrict__ Nv)
{
    int bh = blockIdx.x;
    int tid = threadIdx.x;
    int l = tid >> 2, dq = tid & 3;
    float m16[16];
    float gm = -1e30f;
    #pragma unroll
    for (int c = 0; c < 16; c++) {
        m16[c] = pm[((size_t)bh * 16 + c) * 64 + l];
        gm = fmaxf(gm, m16[c]);
    }
    float gs = 0.f;
    float e16[16];
    #pragma unroll
    for (int c = 0; c < 16; c++) {
        float e = expf(m16[c] - gm);
        e16[c] = e;
        gs += ps[((size_t)bh * 16 + c) * 64 + l] * e;
    }
    f32x4 a[4] = {};
    for (int c = 0; c < 16; c++) {
        float e = e16[c];
        const float* pp = pacc + (((size_t)bh * 16 + c) * 64 + l) * 64 + dq * 16;
        #pragma unroll
        for (int i = 0; i < 4; i++) {
            f32x4 t = *(const f32x4*)&pp[4 * i];
            a[i] += e * t;
        }
    }
    float inv = 1.0f / gs;
    float* np = Nv + (size_t)bh * 4096 + l * 64 + dq * 16;
    #pragma unroll
    for (int i = 0; i < 4; i++) {
        f32x4 o = a[i] * inv;
        *(f32x4*)&np[4 * i] = o;
    }
}

// ---------------- PNv = P @ Nv ----------------
__global__ __launch_bounds__(256) void pnv_kernel(const float* __restrict__ P,
                                                  const float* __restrict__ Nv,
                                                  float* __restrict__ PNv)
{
    int bh = blockIdx.x, tid = threadIdx.x;
    __shared__ float pb[64][65], nb[64][65];
    for (int i = tid; i < 4096; i += 256) {
        pb[i >> 6][i & 63] = P[(size_t)bh * 4096 + i];
        nb[i >> 6][i & 63] = Nv[(size_t)bh * 4096 + i];
    }
    __syncthreads();
    int r = tid >> 2, c0 = (tid & 3) << 4;
    for (int j = 0; j < 16; j++) {
        int cc = c0 + j; float acc = 0.f;
        for (int kx = 0; kx < 64; kx++) acc += pb[r][kx] * nb[kx][cc];
        PNv[(size_t)bh * 4096 + r * 64 + cc] = acc;
    }
}

// ---------------- y = softmax(q @ kl^T) @ PNv -> hi/lo bf16 (B,T,C) ----------------
__global__ __launch_bounds__(256) void y_kernel(const float* __restrict__ q,
                                                const float* __restrict__ kl,
                                                const float* __restrict__ PNv,
                                                bf16_t* __restrict__ yhi,
                                                bf16_t* __restrict__ ylo)
{
    int bh = blockIdx.y;
    int t0 = blockIdx.x * 64;
    int tid = threadIdx.x;
    __shared__ float qch[64][65], klb[64][65], pnv[64][65], srow[64][65];
    const float* qp = q + ((size_t)bh * SEQ + t0) * HS;
    for (int i = tid; i < 4096; i += 256) {
        qch[i >> 6][i & 63] = qp[i];
        klb[i >> 6][i & 63] = kl[(size_t)bh * 4096 + i];
        pnv[i >> 6][i & 63] = PNv[(size_t)bh * 4096 + i];
    }
    __syncthreads();
    int t = tid >> 2, l0 = (tid & 3) << 4;
    for (int j = 0; j < 16; j++) {
        int l = l0 + j; float acc = 0.f;
        for (int d = 0; d < 64; d++) acc += qch[t][d] * klb[l][d];
        srow[t][l] = acc;
    }
    __syncthreads();
    float m = -1e30f;
    for (int l = 0; l < 64; l++) m = fmaxf(m, srow[t][l]);
    float s = 0.f;
    for (int l = 0; l < 64; l++) s += expf(srow[t][l] - m);
    float inv = 1.0f / s;
    int d0 = (tid & 3) << 4;
    float acc[16] = {};
    for (int l = 0; l < 64; l++) {
        float w = expf(srow[t][l] - m) * inv;
        for (int j = 0; j < 16; j++) acc[j] += w * pnv[l][d0 + j];
    }
    int b = bh >> 4, h = bh & 15;
    size_t o = ((size_t)(b * SEQ) + t0 + t) * CDIM + h * HS + d0;
    for (int j = 0; j < 16; j++) {
        float v = acc[j];
        bf16_t hh = (bf16_t)v;
        yhi[o + j] = hh;
        ylo[o + j] = (bf16_t)(v - (float)hh);
    }
}

// ---------------- launch ----------------
extern "C" void kernel_launch(void* const* d_in, const int* in_sizes, int n_in,
                              void* d_out, int out_size, void* d_ws, size_t ws_size,
                              hipStream_t stream)
{
    const float* x  = (const float*)d_in[0];
    const float* Wa = (const float*)d_in[1];
    const float* Wp = (const float*)d_in[2];
    float* out = (float*)d_out;
    float* W = (float*)d_ws;

    // float-slot offsets
    const size_t off_q    = 0;
    const size_t off_k    = 16777216;
    const size_t off_v    = 33554432;
    const size_t off_ql   = 50331648;
    const size_t off_kl   = off_ql + 262144;
    const size_t off_P    = off_kl + 262144;
    const size_t off_Nv   = off_P  + 262144;
    const size_t off_PNv  = off_Nv + 262144;
    const size_t off_WatH = off_PNv + 262144;
    const size_t off_WatL = off_WatH + 1572864;
    const size_t off_WptH = off_WatL + 1572864;
    const size_t off_WptL = off_WptH + 524288;
    const size_t off_pm   = off_WptL + 524288;
    const size_t off_ps   = off_pm + 65536;
    const size_t off_pacc = off_ps + 65536;
    const size_t need = (off_pacc + 4194304) * sizeof(float);   // ~240.6 MB
    if (ws_size < need) {
        fprintf(stderr, "[nystrom] ws too small: have %zu need %zu\n", ws_size, need);
        return;
    }

    float* q    = W + off_q;
    float* k    = W + off_k;
    float* v    = W + off_v;
    float* ql   = W + off_ql;
    float* kl   = W + off_kl;
    float* P    = W + off_P;
    float* Nv   = W + off_Nv;
    float* PNv  = W + off_PNv;
    bf16_t* WatH = (bf16_t*)(W + off_WatH);
    bf16_t* WatL = (bf16_t*)(W + off_WatL);
    bf16_t* WptH = (bf16_t*)(W + off_WptH);
    bf16_t* WptL = (bf16_t*)(W + off_WptL);
    float* pm   = W + off_pm;
    float* ps   = W + off_ps;
    float* pacc = W + off_pacc;
    bf16_t* yhi = (bf16_t*)(W + off_k);       // alias k (dead after nv_partial)
    bf16_t* ylo = yhi + (size_t)MROWS * CDIM;

    transpose_split<<<dim3(N3 / 64, KDIM / 64), 256, 0, stream>>>(Wa, WatH, WatL, KDIM, N3);
    transpose_split<<<dim3(CDIM / 64, KDIM / 64), 256, 0, stream>>>(Wp, WptH, WptL, KDIM, CDIM);
    gemm_split<<<dim3(N3 / 128, MROWS / 128), 256, 0, stream>>>(x, nullptr, nullptr,
                                                                WatH, WatL,
                                                                nullptr, q, k, v, N3, 1);
    landmark_kernel<<<262144 / 256, 256, 0, stream>>>(q, k, ql, kl);
    pinv_kernel<<<64, 256, 0, stream>>>(ql, kl, P);
    nv_partial<<<dim3(16, 64), 256, 0, stream>>>(ql, k, v, pm, ps, pacc);
    nv_combine<<<64, 256, 0, stream>>>(pm, ps, pacc, Nv);
    pnv_kernel<<<64, 256, 0, stream>>>(P, Nv, PNv);
    y_kernel<<<dim3(64, 64), 256, 0, stream>>>(q, kl, PNv, yhi, ylo);
    gemm_split<<<dim3(CDIM / 128, MROWS / 128), 256, 0, stream>>>(nullptr, yhi, ylo,
                                                                  WptH, WptL,
                                                                  out, nullptr, nullptr, nullptr, CDIM, 0);
}